// Round 7
// baseline (315.677 us; speedup 1.0000x reference)
//
#include <hip/hip_runtime.h>
#include <hip/hip_bf16.h>
#include <stdint.h>

#define NN 50000
#define NE 800000
#define CC 96
#define NL 3
#define NMT 3125          // M-tiles (16 nodes each)

// Bucketized edge lists: CAP slots per destination node. Degrees ~ Poisson(16);
// P(max degree >= 64) ~ 1e-13 -> CAP=64 is safe, and the pos<CAP guard makes
// the impossible overflow non-corrupting (drops an edge instead of OOB write).
#define CAP 64
#define CAPSH 6

// fp16 fragment-packed weights: per layer: 6 tcol x 6 sets (0-2 Wc gates, 3-5 Whh gates)
// x 3 ks x 64 lanes x 8 fp16 = 55296 elems = 108 KB
#define ELEMS_PER_LAYER 55296

// XCD-partitioned fill: 8 groups (group = blockIdx%8 -> XCD id under the
// round-robin dispatch heuristic). Each group scans ALL edges, scatters only
// dsts in its 6250-node range -> each group's ssrc slice (0.8 MB) + cursor
// slice (25 KB) stay in ONE XCD's L2. (R5 post-mortem: LDS-counter fill and
// cooperative fill both regressed badly; 800K pipelined device atomics at
// ~55-58 us IS the measured floor for the build phase.)
#define FILL_GROUPS 8
#define FILL_GROUP_BLOCKS 400
#define FILL_BLOCKS (FILL_GROUPS*FILL_GROUP_BLOCKS)   // 3200
#define NODES_PER_GROUP (NN/FILL_GROUPS)              // 6250 exact

// fused setup dispatch: fill blocks (scatter-bound) then prep blocks (VALU/VMEM)
#define PREP_ITEMS (NN*CC/8 + NL*288*CC + 288*CC)
#define PREP_BLOCKS ((PREP_ITEMS + 255)/256)

typedef _Float16 f16x8 __attribute__((ext_vector_type(8)));
typedef float f32x4 __attribute__((ext_vector_type(4)));
typedef uint16_t u16x8 __attribute__((ext_vector_type(8)));

__device__ __forceinline__ uint16_t f2h(float f){
  _Float16 h = (_Float16)f;
  return __builtin_bit_cast(uint16_t, h);
}
__device__ __forceinline__ float h2f(uint16_t u){
  return (float)__builtin_bit_cast(_Float16, u);
}

// fe(tcol,g2,ks,lane,j); g2: 0-2 Wc r/z/n, 3-5 Whh r/z/n.
// B-frag (16x16x32): element (k = ks*32 + (lane>>4)*8 + j, n = lane&15).
__device__ __forceinline__ size_t frag_elem(int tcol, int g2, int ks, int lane, int j){
  return (((size_t)(tcol*6 + g2)*3 + ks)*64 + lane)*8 + j;
}

// Fused setup: blocks [0,FILL_BLOCKS) do the XCD-partitioned bucket fill with a
// single atomicAdd-with-return (returned cursor IS the degree count). Blocks
// [FILL_BLOCKS, ...) do fp16 x-table cvt + weight fold/pack (VALU/VMEM bound).
__global__ void k_setup(const int* __restrict__ srcv, const int* __restrict__ dstv,
                        int* __restrict__ cursor, uint16_t* __restrict__ ssrc,
                        const float4* __restrict__ x, u16x8* __restrict__ xh,
                        const float* __restrict__ weight, const float* __restrict__ w_ih,
                        const float* __restrict__ w_hh, uint16_t* __restrict__ gw){
  if(blockIdx.x < FILL_BLOCKS){
    int g  = blockIdx.x & 7;          // group == XCD id (round-robin dispatch)
    int bg = blockIdx.x >> 3;         // block index within group
    int dlo = g * NODES_PER_GROUP;
    int dhi = dlo + NODES_PER_GROUP;
    const int tpg = FILL_GROUP_BLOCKS*256;      // 102400 threads/group
    for(int e = bg*256 + threadIdx.x; e < NE; e += tpg){
      int d = dstv[e];
      if(d >= dlo && d < dhi){
        int s = srcv[e];
        int pos = atomicAdd(&cursor[d], 1);
        if(pos < CAP) ssrc[((size_t)d << CAPSH) + pos] = (uint16_t)s;
      }
    }
    return;
  }
  int idx = (blockIdx.x - FILL_BLOCKS)*256 + threadIdx.x;
  const int N8 = NN*CC/8;          // 600000
  if(idx < N8){
    float4 a = x[idx*2], b = x[idx*2+1];
    u16x8 o;
    o[0]=f2h(a.x); o[1]=f2h(a.y); o[2]=f2h(a.z); o[3]=f2h(a.w);
    o[4]=f2h(b.x); o[5]=f2h(b.y); o[6]=f2h(b.z); o[7]=f2h(b.w);
    xh[idx] = o;
    return;
  }
  int pidx = idx - N8;
  const int TOT1 = NL*288*CC;      // Wc: (l, col, k)
  const int TOT2 = 288*CC;         // Whh: (col, k), replicated to all layers
  if(pidx < TOT1){
    int k = pidx % CC;
    int col = (pidx / CC) % 288;
    int l = pidx / (CC*288);
    // Wc[k][col] = sum_k2 weight[l][k][k2] * w_ih[col][k2]
    const float4* wr = (const float4*)(weight + (size_t)(l*CC + k)*CC);
    const float4* ir = (const float4*)(w_ih + (size_t)col*CC);
    float acc = 0.f;
    #pragma unroll 4
    for(int k2=0;k2<CC/4;k2++){
      float4 a = wr[k2], b = ir[k2];
      acc += a.x*b.x + a.y*b.y + a.z*b.z + a.w*b.w;
    }
    int g = col / 96, cg = col % 96;
    int tcol = cg >> 4, n = cg & 15;
    int ks = k >> 5, r = (k & 31) >> 3, j = k & 7;
    int lane = r*16 + n;
    gw[(size_t)l*ELEMS_PER_LAYER + frag_elem(tcol, g, ks, lane, j)] = f2h(acc);
  } else {
    int idx2 = pidx - TOT1;
    if(idx2 < TOT2){
      int k = idx2 % CC;
      int col = idx2 / CC;
      uint16_t h = f2h(w_hh[(size_t)col*CC + k]);   // gh = x @ w_hh^T: B[k][col] = w_hh[col][k]
      int g = col / 96, cg = col % 96;
      int tcol = cg >> 4, n = cg & 15;
      int ks = k >> 5, r = (k & 31) >> 3, j = k & 7;
      int lane = r*16 + n;
      size_t fe = frag_elem(tcol, 3+g, ks, lane, j);
      #pragma unroll
      for(int l=0;l<NL;l++) gw[(size_t)l*ELEMS_PER_LAYER + fe] = h;
    }
  }
}

#define MFMA16(A,B,C) __builtin_amdgcn_mfma_f32_16x16x32_f16(A,B,C,0,0,0)

// Fused aggregate + dual-GEMM + GRU. One block = 16 waves; wave w owns mtile
// w*256 + blockIdx.x (cyclic). Block aggregates its 256 nodes into LDS in
// A-fragment chunk-major layout agg[chunk=c8][node_local][16B]; ping-pong h
// tables (no cross-block hazard). LDS: 108 KB weights + 48 KB agg = 156 KB.
// R7 fix: __launch_bounds__(1024, 4) — LDS already forces 1 block/CU
// (= 4 waves/EU), so declare it: VGPR budget 64 -> 128. R6's 64-VGPR cap
// spilled the 8-deep gather to scratch (WRITE_SIZE 54 MB, ~44 MB of it spill).
__global__ __launch_bounds__(1024, 4) void k_layer(
    const uint16_t* __restrict__ xh_cur, uint16_t* __restrict__ xh_nxt,
    const int* __restrict__ counts, const uint16_t* __restrict__ ssrc,
    const uint16_t* __restrict__ gw_l,
    const float* __restrict__ b_ih, const float* __restrict__ b_hh,
    float* __restrict__ out_f)
{
  __shared__ __align__(16) uint16_t lw[ELEMS_PER_LAYER];   // 110592 B
  __shared__ u16x8 aggl[12*256];                           //  49152 B

  const int tid = threadIdx.x;
  const int wave = tid >> 6;
  const int lane = tid & 63;
  const int nidx = lane & 15;
  const int quad = lane >> 4;
  const int mtile = wave*256 + blockIdx.x;      // cyclic: all 256 blocks busy
  const bool valid = (mtile < NMT);
  const int mt = valid ? mtile : 0;

  // h-row A fragments (global, ~600 cyc) — issued first, drain at the barrier
  f16x8 ax[3];
  {
    size_t arow = (size_t)(mt*16 + nidx)*CC;
    #pragma unroll
    for(int ks=0; ks<3; ks++)
      ax[ks] = *reinterpret_cast<const f16x8*>(xh_cur + arow + ks*32 + quad*8);
  }

  // stage weights: 6912 uint4 chunks over 1024 threads
  {
    const uint4* src = (const uint4*)gw_l;
    uint4* dst = (uint4*)lw;
    #pragma unroll
    for(int i=0;i<7;i++){
      int chunk = i*1024 + tid;
      if(chunk < ELEMS_PER_LAYER/8) dst[chunk] = src[chunk];
    }
  }

  // aggregation into LDS: thread -> (node_local = tid>>2, chunks c8b..c8b+2)
  // 4 threads/node cover 12 chunks; 8-deep edge unroll = 24 16B gathers in
  // flight per thread (fits the 128-VGPR budget, no spill).
  {
    int nl_ = tid >> 2;               // 0..255 ; nl_>>4 == wave (uniform guard)
    int c8b = (tid & 3)*3;            // 0,3,6,9
    if(valid){
      int node = mt*16 + (nl_ & 15);
      int cnt = counts[node]; if(cnt > CAP) cnt = CAP;   // cannot trigger
      const u16x8* xg = (const u16x8*)xh_cur;
      float a0[8], a1[8], a2[8];
      #pragma unroll
      for(int t=0;t<8;t++){ a0[t]=0.f; a1[t]=0.f; a2[t]=0.f; }
      int j0 = node << CAPSH;
      int j1 = j0 + cnt;
      int j = j0;
      for(; j+8 <= j1; j+=8){
        u16x8 sv = *reinterpret_cast<const u16x8*>(ssrc + j);  // 16B, 16B-aligned
        size_t b0 = (size_t)sv[0]*12 + c8b;
        size_t b1 = (size_t)sv[1]*12 + c8b;
        size_t b2 = (size_t)sv[2]*12 + c8b;
        size_t b3 = (size_t)sv[3]*12 + c8b;
        size_t b4 = (size_t)sv[4]*12 + c8b;
        size_t b5 = (size_t)sv[5]*12 + c8b;
        size_t b6 = (size_t)sv[6]*12 + c8b;
        size_t b7 = (size_t)sv[7]*12 + c8b;
        u16x8 v00=xg[b0], v01=xg[b0+1], v02=xg[b0+2];
        u16x8 v10=xg[b1], v11=xg[b1+1], v12=xg[b1+2];
        u16x8 v20=xg[b2], v21=xg[b2+1], v22=xg[b2+2];
        u16x8 v30=xg[b3], v31=xg[b3+1], v32=xg[b3+2];
        u16x8 v40=xg[b4], v41=xg[b4+1], v42=xg[b4+2];
        u16x8 v50=xg[b5], v51=xg[b5+1], v52=xg[b5+2];
        u16x8 v60=xg[b6], v61=xg[b6+1], v62=xg[b6+2];
        u16x8 v70=xg[b7], v71=xg[b7+1], v72=xg[b7+2];
        #pragma unroll
        for(int t=0;t<8;t++){
          a0[t] += ((h2f(v00[t])+h2f(v10[t]))+(h2f(v20[t])+h2f(v30[t])))
                 + ((h2f(v40[t])+h2f(v50[t]))+(h2f(v60[t])+h2f(v70[t])));
          a1[t] += ((h2f(v01[t])+h2f(v11[t]))+(h2f(v21[t])+h2f(v31[t])))
                 + ((h2f(v41[t])+h2f(v51[t]))+(h2f(v61[t])+h2f(v71[t])));
          a2[t] += ((h2f(v02[t])+h2f(v12[t]))+(h2f(v22[t])+h2f(v32[t])))
                 + ((h2f(v42[t])+h2f(v52[t]))+(h2f(v62[t])+h2f(v72[t])));
        }
      }
      for(; j < j1; j++){
        size_t b = (size_t)ssrc[j]*12 + c8b;
        u16x8 v0=xg[b], v1=xg[b+1], v2=xg[b+2];
        #pragma unroll
        for(int t=0;t<8;t++){ a0[t]+=h2f(v0[t]); a1[t]+=h2f(v1[t]); a2[t]+=h2f(v2[t]); }
      }
      u16x8 w0, w1, w2;
      #pragma unroll
      for(int t=0;t<8;t++){ w0[t]=f2h(a0[t]); w1[t]=f2h(a1[t]); w2[t]=f2h(a2[t]); }
      aggl[(c8b+0)*256 + nl_] = w0;
      aggl[(c8b+1)*256 + nl_] = w1;
      aggl[(c8b+2)*256 + nl_] = w2;
    }
  }
  __syncthreads();                        // the only barrier
  if(!valid) return;                      // idle waves exit after barrier

  // aggregate A fragments from LDS (chunk = ks*4+quad, row = own wave's nodes)
  f16x8 as[3];
  #pragma unroll
  for(int ks=0; ks<3; ks++)
    as[ks] = *reinterpret_cast<const f16x8*>(&aggl[(ks*4+quad)*256 + wave*16 + nidx]);

  #pragma unroll 1
  for(int tcol=0; tcol<6; tcol++){
    f32x4 air = {0.f,0.f,0.f,0.f}, aiz = {0.f,0.f,0.f,0.f}, ain = {0.f,0.f,0.f,0.f};
    f32x4 ahr = {0.f,0.f,0.f,0.f}, ahz = {0.f,0.f,0.f,0.f}, ahn = {0.f,0.f,0.f,0.f};

    #pragma unroll
    for(int ks=0; ks<3; ks++){
      const uint16_t* base = lw + (((size_t)tcol*6)*3 + ks)*512 + lane*8;
      #define BFRAG(g2) (*reinterpret_cast<const f16x8*>(base + (size_t)(g2)*3*512))
      air = MFMA16(as[ks], BFRAG(0), air);
      aiz = MFMA16(as[ks], BFRAG(1), aiz);
      ain = MFMA16(as[ks], BFRAG(2), ain);
      ahr = MFMA16(ax[ks], BFRAG(3), ahr);
      ahz = MFMA16(ax[ks], BFRAG(4), ahz);
      ahn = MFMA16(ax[ks], BFRAG(5), ahn);
      #undef BFRAG
    }

    int c = tcol*16 + nidx;
    float bir_ = b_ih[c], biz_ = b_ih[CC+c], bin_ = b_ih[2*CC+c];
    float bhr_ = b_hh[c], bhz_ = b_hh[CC+c], bhn_ = b_hh[2*CC+c];

    #pragma unroll
    for(int r=0;r<4;r++){
      int node = mtile*16 + quad*4 + r;   // C/D: row = quad*4 + reg, col = lane&15
      float ir  = air[r] + bir_;
      float iz  = aiz[r] + biz_;
      float in_ = ain[r] + bin_;
      float hr  = ahr[r] + bhr_;
      float hz  = ahz[r] + bhz_;
      float hn  = ahn[r] + bhn_;
      float rg = 1.f/(1.f + __expf(-(ir+hr)));
      float zg = 1.f/(1.f + __expf(-(iz+hz)));
      float nv = in_ + rg*hn;
      float av = fminf(fabsf(nv), 15.f);
      float e2 = __expf(2.f*av);
      float tg = 1.f - 2.f/(e2 + 1.f);
      tg = (nv < 0.f)? -tg : tg;
      size_t oi = (size_t)node*CC + c;
      float hp = h2f(xh_cur[oi]);         // h state lives in the fp16 table
      float h = (1.f - zg)*tg + zg*hp;
      if(out_f) out_f[oi] = h;            // final layer: f32 output only
      else      xh_nxt[oi] = f2h(h);      // intermediate layers: fp16 ping-pong
    }
  }
}

extern "C" void kernel_launch(void* const* d_in, const int* in_sizes, int n_in,
                              void* d_out, int out_size, void* d_ws, size_t ws_size,
                              hipStream_t stream){
  const float* x0     = (const float*)d_in[0];
  const int*   ei     = (const int*)d_in[1];
  const float* weight = (const float*)d_in[2];
  const float* w_ih   = (const float*)d_in[3];
  const float* w_hh   = (const float*)d_in[4];
  const float* b_ih   = (const float*)d_in[5];
  const float* b_hh   = (const float*)d_in[6];
  float* out = (float*)d_out;

  const int* srcv = ei;        // edge_index[0]
  const int* dstv = ei + NE;   // edge_index[1]

  char* ws = (char*)d_ws;
  size_t off = 0;
  auto carve = [&](size_t bytes)->char*{
    char* p = ws + off;
    off += (bytes + 255) & ~(size_t)255;
    return p;
  };
  int* cursor     = (int*)carve((size_t)NN*4);                   // degree counters
  uint16_t* ssrc  = (uint16_t*)carve((size_t)NN*CAP*2);          // bucketized src ids (6.4 MB)
  uint16_t* xh16A = (uint16_t*)carve((size_t)NN*CC*2);           // fp16 h table ping
  uint16_t* xh16B = (uint16_t*)carve((size_t)NN*CC*2);           // fp16 h table pong
  uint16_t* gw    = (uint16_t*)carve((size_t)NL*ELEMS_PER_LAYER*2);

  // Single-pass bucket build + prep, fused into one dispatch (disjoint
  // block ranges; scatter-bound fill overlaps VALU/VMEM-bound prep).
  hipMemsetAsync(cursor, 0, (size_t)NN*4, stream);
  k_setup<<<FILL_BLOCKS + PREP_BLOCKS, 256, 0, stream>>>(
      srcv, dstv, cursor, ssrc, (const float4*)x0, (u16x8*)xh16A, weight, w_ih, w_hh, gw);

  uint16_t* xh_cur = xh16A;
  uint16_t* xh_nxt = xh16B;
  for(int l=0; l<NL; l++){
    float* out_f = (l==NL-1) ? out : nullptr;
    k_layer<<<256, 1024, 0, stream>>>(xh_cur, xh_nxt, cursor, ssrc,
                                      gw + (size_t)l*ELEMS_PER_LAYER,
                                      b_ih, b_hh, out_f);
    uint16_t* t = xh_cur; xh_cur = xh_nxt; xh_nxt = t;
  }
}

// Round 8
// 270.551 us; speedup vs baseline: 1.1668x; 1.1668x over previous
//
#include <hip/hip_runtime.h>
#include <hip/hip_bf16.h>
#include <stdint.h>

#define NN 50000
#define NE 800000
#define CC 96
#define NL 3
#define NMT 3125          // M-tiles (16 nodes each)

// Bucketized edge lists: CAP slots per destination node. Degrees ~ Poisson(16);
// P(max degree >= 64) ~ 1e-13 -> CAP=64 is safe, and the pos<CAP guard makes
// the impossible overflow non-corrupting (drops an edge instead of OOB write).
#define CAP 64
#define CAPSH 6

// fp16 fragment-packed weights: per layer: 6 tcol x 6 sets (0-2 Wc gates, 3-5 Whh gates)
// x 3 ks x 64 lanes x 8 fp16 = 55296 elems = 108 KB
#define ELEMS_PER_LAYER 55296

// XCD-partitioned fill: 8 groups (group = blockIdx%8 -> XCD id under the
// round-robin dispatch heuristic). Each group scans ALL edges, scatters only
// dsts in its 6250-node range -> each group's ssrc slice (0.8 MB) + cursor
// slice (25 KB) stay in ONE XCD's L2. (R5 post-mortem: LDS-counter fill and
// cooperative fill both regressed badly; 800K pipelined device atomics at
// ~55-58 us IS the measured floor for the build phase.)
#define FILL_GROUPS 8
#define FILL_GROUP_BLOCKS 400
#define FILL_BLOCKS (FILL_GROUPS*FILL_GROUP_BLOCKS)   // 3200
#define NODES_PER_GROUP (NN/FILL_GROUPS)              // 6250 exact

// fused setup dispatch: fill blocks (scatter-bound) then prep blocks (VALU/VMEM)
#define PREP_ITEMS (NN*CC/8 + NL*288*CC + 288*CC)
#define PREP_BLOCKS ((PREP_ITEMS + 255)/256)

typedef _Float16 f16x8 __attribute__((ext_vector_type(8)));
typedef float f32x4 __attribute__((ext_vector_type(4)));
typedef uint16_t u16x8 __attribute__((ext_vector_type(8)));

__device__ __forceinline__ uint16_t f2h(float f){
  _Float16 h = (_Float16)f;
  return __builtin_bit_cast(uint16_t, h);
}
__device__ __forceinline__ float h2f(uint16_t u){
  return (float)__builtin_bit_cast(_Float16, u);
}

// fe(tcol,g2,ks,lane,j); g2: 0-2 Wc r/z/n, 3-5 Whh r/z/n.
// B-frag (16x16x32): element (k = ks*32 + (lane>>4)*8 + j, n = lane&15).
__device__ __forceinline__ size_t frag_elem(int tcol, int g2, int ks, int lane, int j){
  return (((size_t)(tcol*6 + g2)*3 + ks)*64 + lane)*8 + j;
}

// Fused setup: blocks [0,FILL_BLOCKS) do the XCD-partitioned bucket fill with a
// single atomicAdd-with-return (returned cursor IS the degree count). Blocks
// [FILL_BLOCKS, ...) do fp16 x-table cvt + weight fold/pack (VALU/VMEM bound).
__global__ void k_setup(const int* __restrict__ srcv, const int* __restrict__ dstv,
                        int* __restrict__ cursor, uint16_t* __restrict__ ssrc,
                        const float4* __restrict__ x, u16x8* __restrict__ xh,
                        const float* __restrict__ weight, const float* __restrict__ w_ih,
                        const float* __restrict__ w_hh, uint16_t* __restrict__ gw){
  if(blockIdx.x < FILL_BLOCKS){
    int g  = blockIdx.x & 7;          // group == XCD id (round-robin dispatch)
    int bg = blockIdx.x >> 3;         // block index within group
    int dlo = g * NODES_PER_GROUP;
    int dhi = dlo + NODES_PER_GROUP;
    const int tpg = FILL_GROUP_BLOCKS*256;      // 102400 threads/group
    for(int e = bg*256 + threadIdx.x; e < NE; e += tpg){
      int d = dstv[e];
      if(d >= dlo && d < dhi){
        int s = srcv[e];
        int pos = atomicAdd(&cursor[d], 1);
        if(pos < CAP) ssrc[((size_t)d << CAPSH) + pos] = (uint16_t)s;
      }
    }
    return;
  }
  int idx = (blockIdx.x - FILL_BLOCKS)*256 + threadIdx.x;
  const int N8 = NN*CC/8;          // 600000
  if(idx < N8){
    float4 a = x[idx*2], b = x[idx*2+1];
    u16x8 o;
    o[0]=f2h(a.x); o[1]=f2h(a.y); o[2]=f2h(a.z); o[3]=f2h(a.w);
    o[4]=f2h(b.x); o[5]=f2h(b.y); o[6]=f2h(b.z); o[7]=f2h(b.w);
    xh[idx] = o;
    return;
  }
  int pidx = idx - N8;
  const int TOT1 = NL*288*CC;      // Wc: (l, col, k)
  const int TOT2 = 288*CC;         // Whh: (col, k), replicated to all layers
  if(pidx < TOT1){
    int k = pidx % CC;
    int col = (pidx / CC) % 288;
    int l = pidx / (CC*288);
    // Wc[k][col] = sum_k2 weight[l][k][k2] * w_ih[col][k2]
    const float4* wr = (const float4*)(weight + (size_t)(l*CC + k)*CC);
    const float4* ir = (const float4*)(w_ih + (size_t)col*CC);
    float acc = 0.f;
    #pragma unroll 4
    for(int k2=0;k2<CC/4;k2++){
      float4 a = wr[k2], b = ir[k2];
      acc += a.x*b.x + a.y*b.y + a.z*b.z + a.w*b.w;
    }
    int g = col / 96, cg = col % 96;
    int tcol = cg >> 4, n = cg & 15;
    int ks = k >> 5, r = (k & 31) >> 3, j = k & 7;
    int lane = r*16 + n;
    gw[(size_t)l*ELEMS_PER_LAYER + frag_elem(tcol, g, ks, lane, j)] = f2h(acc);
  } else {
    int idx2 = pidx - TOT1;
    if(idx2 < TOT2){
      int k = idx2 % CC;
      int col = idx2 / CC;
      uint16_t h = f2h(w_hh[(size_t)col*CC + k]);   // gh = x @ w_hh^T: B[k][col] = w_hh[col][k]
      int g = col / 96, cg = col % 96;
      int tcol = cg >> 4, n = cg & 15;
      int ks = k >> 5, r = (k & 31) >> 3, j = k & 7;
      int lane = r*16 + n;
      size_t fe = frag_elem(tcol, 3+g, ks, lane, j);
      #pragma unroll
      for(int l=0;l<NL;l++) gw[(size_t)l*ELEMS_PER_LAYER + fe] = h;
    }
  }
}

#define MFMA16(A,B,C) __builtin_amdgcn_mfma_f32_16x16x32_f16(A,B,C,0,0,0)

// Fused aggregate + dual-GEMM + GRU — ZERO-LDS version (R8).
// R7 post-mortem: with 156 KB LDS the kernel is pinned at 1 block/CU =
// 16 waves/CU and the latency-bound gather (MfmaUtil 3%, VALU 22%, occ 33%,
// 2.7 TB/s) can't hide. Fixes here:
//  * aggregate IN REGISTERS (R4-proven mapping: thread owns node mt*16+nidx,
//    chunks {quad,4+quad,8+quad} == its lane's A-fragments) — no aggl, no
//    barrier;
//  * B-fragments read straight from global gw_l (324 KB, read-only,
//    L2-resident; each frag load is lane*16B = perfectly coalesced 1KB);
//  * 256-thread blocks (4 waves, 4 mtiles) — occupancy becomes wave-granular,
//    VGPR-driven: 20-32 waves/CU expected vs 16 today.
// Gather depth = 4 edges/iter (R3-proven; 8-deep spilled at 64 VGPR).
__global__ __launch_bounds__(256) void k_layer(
    const uint16_t* __restrict__ xh_cur, uint16_t* __restrict__ xh_nxt,
    const int* __restrict__ counts, const uint16_t* __restrict__ ssrc,
    const uint16_t* __restrict__ gw_l,
    const float* __restrict__ b_ih, const float* __restrict__ b_hh,
    float* __restrict__ out_f)
{
  const int tid  = threadIdx.x;
  const int wave = tid >> 6;
  const int lane = tid & 63;
  const int nidx = lane & 15;
  const int quad = lane >> 4;
  const int mtile = blockIdx.x*4 + wave;
  if(mtile >= NMT) return;               // uniform whole-wave exit (no barriers)

  // ---- register aggregation: 4-deep edge unroll, 12 16B gathers in flight --
  float a0[8], a1[8], a2[8];
  #pragma unroll
  for(int t=0;t<8;t++){ a0[t]=0.f; a1[t]=0.f; a2[t]=0.f; }
  {
    int node = mtile*16 + nidx;
    int cnt = counts[node]; if(cnt > CAP) cnt = CAP;   // cannot trigger
    const u16x8* xg = (const u16x8*)xh_cur;
    int j0 = node << CAPSH;
    int j1 = j0 + cnt;
    int j = j0;
    for(; j+4 <= j1; j+=4){
      ushort4 sv = *reinterpret_cast<const ushort4*>(ssrc + j);  // 8B, 8B-aligned
      size_t b0 = (size_t)sv.x*12 + quad;
      size_t b1 = (size_t)sv.y*12 + quad;
      size_t b2 = (size_t)sv.z*12 + quad;
      size_t b3 = (size_t)sv.w*12 + quad;
      u16x8 v00=xg[b0],   v01=xg[b0+4], v02=xg[b0+8];
      u16x8 v10=xg[b1],   v11=xg[b1+4], v12=xg[b1+8];
      u16x8 v20=xg[b2],   v21=xg[b2+4], v22=xg[b2+8];
      u16x8 v30=xg[b3],   v31=xg[b3+4], v32=xg[b3+8];
      #pragma unroll
      for(int t=0;t<8;t++){
        a0[t] += (h2f(v00[t])+h2f(v10[t])) + (h2f(v20[t])+h2f(v30[t]));
        a1[t] += (h2f(v01[t])+h2f(v11[t])) + (h2f(v21[t])+h2f(v31[t]));
        a2[t] += (h2f(v02[t])+h2f(v12[t])) + (h2f(v22[t])+h2f(v32[t]));
      }
    }
    for(; j < j1; j++){
      size_t b = (size_t)ssrc[j]*12 + quad;
      u16x8 v0=xg[b], v1=xg[b+4], v2=xg[b+8];
      #pragma unroll
      for(int t=0;t<8;t++){ a0[t]+=h2f(v0[t]); a1[t]+=h2f(v1[t]); a2[t]+=h2f(v2[t]); }
    }
  }

  // h-row A fragments (coalesced 64B/quad-group reads of own mtile rows)
  f16x8 ax[3];
  {
    size_t arow = (size_t)(mtile*16 + nidx)*CC;
    #pragma unroll
    for(int ks=0; ks<3; ks++)
      ax[ks] = *reinterpret_cast<const f16x8*>(xh_cur + arow + ks*32 + quad*8);
  }

  // aggregate A fragments straight from the accumulators
  f16x8 as[3];
  #pragma unroll
  for(int t=0;t<8;t++){
    as[0][t]=(_Float16)a0[t]; as[1][t]=(_Float16)a1[t]; as[2][t]=(_Float16)a2[t];
  }

  #pragma unroll 1
  for(int tcol=0; tcol<6; tcol++){
    f32x4 air = {0.f,0.f,0.f,0.f}, aiz = {0.f,0.f,0.f,0.f}, ain = {0.f,0.f,0.f,0.f};
    f32x4 ahr = {0.f,0.f,0.f,0.f}, ahz = {0.f,0.f,0.f,0.f}, ahn = {0.f,0.f,0.f,0.f};

    #pragma unroll
    for(int ks=0; ks<3; ks++){
      // B-fragments from global (L2-broadcast): lane*16B -> 1KB coalesced/instr
      const uint16_t* base = gw_l + (((size_t)tcol*6)*3 + ks)*512 + lane*8;
      #define BFRAG(g2) (*reinterpret_cast<const f16x8*>(base + (size_t)(g2)*3*512))
      air = MFMA16(as[ks], BFRAG(0), air);
      aiz = MFMA16(as[ks], BFRAG(1), aiz);
      ain = MFMA16(as[ks], BFRAG(2), ain);
      ahr = MFMA16(ax[ks], BFRAG(3), ahr);
      ahz = MFMA16(ax[ks], BFRAG(4), ahz);
      ahn = MFMA16(ax[ks], BFRAG(5), ahn);
      #undef BFRAG
    }

    int c = tcol*16 + nidx;
    float bir_ = b_ih[c], biz_ = b_ih[CC+c], bin_ = b_ih[2*CC+c];
    float bhr_ = b_hh[c], bhz_ = b_hh[CC+c], bhn_ = b_hh[2*CC+c];

    #pragma unroll
    for(int r=0;r<4;r++){
      int node = mtile*16 + quad*4 + r;   // C/D: row = quad*4 + reg, col = lane&15
      float ir  = air[r] + bir_;
      float iz  = aiz[r] + biz_;
      float in_ = ain[r] + bin_;
      float hr  = ahr[r] + bhr_;
      float hz  = ahz[r] + bhz_;
      float hn  = ahn[r] + bhn_;
      float rg = 1.f/(1.f + __expf(-(ir+hr)));
      float zg = 1.f/(1.f + __expf(-(iz+hz)));
      float nv = in_ + rg*hn;
      float av = fminf(fabsf(nv), 15.f);
      float e2 = __expf(2.f*av);
      float tg = 1.f - 2.f/(e2 + 1.f);
      tg = (nv < 0.f)? -tg : tg;
      size_t oi = (size_t)node*CC + c;
      float hp = h2f(xh_cur[oi]);         // h state lives in the fp16 table
      float h = (1.f - zg)*tg + zg*hp;
      if(out_f) out_f[oi] = h;            // final layer: f32 output only
      else      xh_nxt[oi] = f2h(h);      // intermediate layers: fp16 ping-pong
    }
  }
}

extern "C" void kernel_launch(void* const* d_in, const int* in_sizes, int n_in,
                              void* d_out, int out_size, void* d_ws, size_t ws_size,
                              hipStream_t stream){
  const float* x0     = (const float*)d_in[0];
  const int*   ei     = (const int*)d_in[1];
  const float* weight = (const float*)d_in[2];
  const float* w_ih   = (const float*)d_in[3];
  const float* w_hh   = (const float*)d_in[4];
  const float* b_ih   = (const float*)d_in[5];
  const float* b_hh   = (const float*)d_in[6];
  float* out = (float*)d_out;

  const int* srcv = ei;        // edge_index[0]
  const int* dstv = ei + NE;   // edge_index[1]

  char* ws = (char*)d_ws;
  size_t off = 0;
  auto carve = [&](size_t bytes)->char*{
    char* p = ws + off;
    off += (bytes + 255) & ~(size_t)255;
    return p;
  };
  int* cursor     = (int*)carve((size_t)NN*4);                   // degree counters
  uint16_t* ssrc  = (uint16_t*)carve((size_t)NN*CAP*2);          // bucketized src ids (6.4 MB)
  uint16_t* xh16A = (uint16_t*)carve((size_t)NN*CC*2);           // fp16 h table ping
  uint16_t* xh16B = (uint16_t*)carve((size_t)NN*CC*2);           // fp16 h table pong
  uint16_t* gw    = (uint16_t*)carve((size_t)NL*ELEMS_PER_LAYER*2);

  // Single-pass bucket build + prep, fused into one dispatch (disjoint
  // block ranges; scatter-bound fill overlaps VALU/VMEM-bound prep).
  hipMemsetAsync(cursor, 0, (size_t)NN*4, stream);
  k_setup<<<FILL_BLOCKS + PREP_BLOCKS, 256, 0, stream>>>(
      srcv, dstv, cursor, ssrc, (const float4*)x0, (u16x8*)xh16A, weight, w_ih, w_hh, gw);

  uint16_t* xh_cur = xh16A;
  uint16_t* xh_nxt = xh16B;
  const int LAYER_BLOCKS = (NMT + 3)/4;     // 782 blocks x 4 waves x 1 mtile
  for(int l=0; l<NL; l++){
    float* out_f = (l==NL-1) ? out : nullptr;
    k_layer<<<LAYER_BLOCKS, 256, 0, stream>>>(xh_cur, xh_nxt, cursor, ssrc,
                                              gw + (size_t)l*ELEMS_PER_LAYER,
                                              b_ih, b_hh, out_f);
    uint16_t* t = xh_cur; xh_cur = xh_nxt; xh_nxt = t;
  }
}

// Round 9
// 252.619 us; speedup vs baseline: 1.2496x; 1.0710x over previous
//
#include <hip/hip_runtime.h>
#include <hip/hip_bf16.h>
#include <stdint.h>

#define NN 50000
#define NE 800000
#define CC 96
#define NL 3
#define NMT 3125          // M-tiles (16 nodes each)

// Bucketized edge lists: CAP slots per destination node. Degrees ~ Poisson(16);
// P(max degree >= 64) ~ 1e-13 -> CAP=64 is safe, and the pos<CAP guard makes
// the impossible overflow non-corrupting (drops an edge instead of OOB write).
#define CAP 64
#define CAPSH 6

// fp16 fragment-packed weights: per layer: 6 tcol x 6 sets (0-2 Wc gates, 3-5 Whh gates)
// x 3 ks x 64 lanes x 8 fp16 = 55296 elems = 108 KB
#define ELEMS_PER_LAYER 55296

// XCD-partitioned fill: 8 groups (group = blockIdx%8 -> XCD id under the
// round-robin dispatch heuristic). Each group scans ALL edges, scatters only
// dsts in its 6250-node range -> each group's ssrc slice (0.8 MB) + cursor
// slice (25 KB) stay in ONE XCD's L2. Floors established R1-R5: 800K pipelined
// device atomics ~55-58 us; LDS-counter fill (225 us) and cooperative fill
// (+95 us) both much worse.
#define FILL_GROUPS 8
#define FILL_GROUP_BLOCKS 400
#define FILL_BLOCKS (FILL_GROUPS*FILL_GROUP_BLOCKS)   // 3200
#define NODES_PER_GROUP (NN/FILL_GROUPS)              // 6250 exact

// fused setup dispatch: fill blocks (scatter-bound) then prep blocks (VALU/VMEM)
#define PREP_ITEMS (NN*CC/8 + NL*288*CC + 288*CC)
#define PREP_BLOCKS ((PREP_ITEMS + 255)/256)

typedef _Float16 f16x8 __attribute__((ext_vector_type(8)));
typedef float f32x4 __attribute__((ext_vector_type(4)));
typedef uint16_t u16x8 __attribute__((ext_vector_type(8)));

__device__ __forceinline__ uint16_t f2h(float f){
  _Float16 h = (_Float16)f;
  return __builtin_bit_cast(uint16_t, h);
}
__device__ __forceinline__ float h2f(uint16_t u){
  return (float)__builtin_bit_cast(_Float16, u);
}

// fe(tcol,g2,ks,lane,j); g2: 0-2 Wc r/z/n, 3-5 Whh r/z/n.
// B-frag (16x16x32): element (k = ks*32 + (lane>>4)*8 + j, n = lane&15).
__device__ __forceinline__ size_t frag_elem(int tcol, int g2, int ks, int lane, int j){
  return (((size_t)(tcol*6 + g2)*3 + ks)*64 + lane)*8 + j;
}

// Fused setup: blocks [0,FILL_BLOCKS) do the XCD-partitioned bucket fill with a
// single atomicAdd-with-return (returned cursor IS the degree count). Blocks
// [FILL_BLOCKS, ...) do fp16 x-table cvt + weight fold/pack (VALU/VMEM bound).
__global__ void k_setup(const int* __restrict__ srcv, const int* __restrict__ dstv,
                        int* __restrict__ cursor, uint16_t* __restrict__ ssrc,
                        const float4* __restrict__ x, u16x8* __restrict__ xh,
                        const float* __restrict__ weight, const float* __restrict__ w_ih,
                        const float* __restrict__ w_hh, uint16_t* __restrict__ gw){
  if(blockIdx.x < FILL_BLOCKS){
    int g  = blockIdx.x & 7;          // group == XCD id (round-robin dispatch)
    int bg = blockIdx.x >> 3;         // block index within group
    int dlo = g * NODES_PER_GROUP;
    int dhi = dlo + NODES_PER_GROUP;
    const int tpg = FILL_GROUP_BLOCKS*256;      // 102400 threads/group
    for(int e = bg*256 + threadIdx.x; e < NE; e += tpg){
      int d = dstv[e];
      if(d >= dlo && d < dhi){
        int s = srcv[e];
        int pos = atomicAdd(&cursor[d], 1);
        if(pos < CAP) ssrc[((size_t)d << CAPSH) + pos] = (uint16_t)s;
      }
    }
    return;
  }
  int idx = (blockIdx.x - FILL_BLOCKS)*256 + threadIdx.x;
  const int N8 = NN*CC/8;          // 600000
  if(idx < N8){
    float4 a = x[idx*2], b = x[idx*2+1];
    u16x8 o;
    o[0]=f2h(a.x); o[1]=f2h(a.y); o[2]=f2h(a.z); o[3]=f2h(a.w);
    o[4]=f2h(b.x); o[5]=f2h(b.y); o[6]=f2h(b.z); o[7]=f2h(b.w);
    xh[idx] = o;
    return;
  }
  int pidx = idx - N8;
  const int TOT1 = NL*288*CC;      // Wc: (l, col, k)
  const int TOT2 = 288*CC;         // Whh: (col, k), replicated to all layers
  if(pidx < TOT1){
    int k = pidx % CC;
    int col = (pidx / CC) % 288;
    int l = pidx / (CC*288);
    // Wc[k][col] = sum_k2 weight[l][k][k2] * w_ih[col][k2]
    const float4* wr = (const float4*)(weight + (size_t)(l*CC + k)*CC);
    const float4* ir = (const float4*)(w_ih + (size_t)col*CC);
    float acc = 0.f;
    #pragma unroll 4
    for(int k2=0;k2<CC/4;k2++){
      float4 a = wr[k2], b = ir[k2];
      acc += a.x*b.x + a.y*b.y + a.z*b.z + a.w*b.w;
    }
    int g = col / 96, cg = col % 96;
    int tcol = cg >> 4, n = cg & 15;
    int ks = k >> 5, r = (k & 31) >> 3, j = k & 7;
    int lane = r*16 + n;
    gw[(size_t)l*ELEMS_PER_LAYER + frag_elem(tcol, g, ks, lane, j)] = f2h(acc);
  } else {
    int idx2 = pidx - TOT1;
    if(idx2 < TOT2){
      int k = idx2 % CC;
      int col = idx2 / CC;
      uint16_t h = f2h(w_hh[(size_t)col*CC + k]);   // gh = x @ w_hh^T: B[k][col] = w_hh[col][k]
      int g = col / 96, cg = col % 96;
      int tcol = cg >> 4, n = cg & 15;
      int ks = k >> 5, r = (k & 31) >> 3, j = k & 7;
      int lane = r*16 + n;
      size_t fe = frag_elem(tcol, 3+g, ks, lane, j);
      #pragma unroll
      for(int l=0;l<NL;l++) gw[(size_t)l*ELEMS_PER_LAYER + fe] = h;
    }
  }
}

#define MFMA16(A,B,C) __builtin_amdgcn_mfma_f32_16x16x32_f16(A,B,C,0,0,0)

// Fused aggregate + dual-GEMM + GRU (R3 structure — proven 256.6 us; three
// structural variants R6-R8 all plateaued 55-64 us -> gather is fabric-bound).
// One block = 16 waves; wave w owns mtile w*256 + blockIdx.x (cyclic). Block
// aggregates its 256 nodes into LDS in A-fragment chunk-major layout
// agg[chunk=c8][node_local][16B]; ping-pong h tables (no cross-block hazard).
// LDS: 108 KB weights + 48 KB agg = 156 KB.
// R9 tweak: gather HEAD (counts + first edge-id vector) hoisted above weight
// staging so the counts->ssrc->gather dependency chain overlaps the staging
// loads; edge-id loads software-pipelined one iteration ahead in the loop.
__global__ __launch_bounds__(1024) void k_layer(
    const uint16_t* __restrict__ xh_cur, uint16_t* __restrict__ xh_nxt,
    const int* __restrict__ counts, const uint16_t* __restrict__ ssrc,
    const uint16_t* __restrict__ gw_l,
    const float* __restrict__ b_ih, const float* __restrict__ b_hh,
    float* __restrict__ out_f)
{
  __shared__ __align__(16) uint16_t lw[ELEMS_PER_LAYER];   // 110592 B
  __shared__ u16x8 aggl[12*256];                           //  49152 B

  const int tid = threadIdx.x;
  const int wave = tid >> 6;
  const int lane = tid & 63;
  const int nidx = lane & 15;
  const int quad = lane >> 4;
  const int mtile = wave*256 + blockIdx.x;      // cyclic: all 256 blocks busy
  const bool valid = (mtile < NMT);
  const int mt = valid ? mtile : 0;

  // ---- gather head issued FIRST: counts -> first id vector (L2 chain) ------
  const int nl_ = tid >> 2;             // 0..255 ; nl_>>4 == wave
  const int c8b = (tid & 3)*3;          // 0,3,6,9
  int cnt = 0, j0 = 0;
  ushort4 sv_pre = {0,0,0,0};
  if(valid){
    int node = mt*16 + (nl_ & 15);
    cnt = counts[node]; if(cnt > CAP) cnt = CAP;   // cannot trigger
    j0 = node << CAPSH;
    if(cnt >= 4) sv_pre = *reinterpret_cast<const ushort4*>(ssrc + j0);
  }

  // h-row A fragments (global, ~600 cyc) — drain at the barrier
  f16x8 ax[3];
  {
    size_t arow = (size_t)(mt*16 + nidx)*CC;
    #pragma unroll
    for(int ks=0; ks<3; ks++)
      ax[ks] = *reinterpret_cast<const f16x8*>(xh_cur + arow + ks*32 + quad*8);
  }

  // stage weights: 6912 uint4 chunks over 1024 threads (overlaps gather head)
  {
    const uint4* src = (const uint4*)gw_l;
    uint4* dst = (uint4*)lw;
    #pragma unroll
    for(int i=0;i<7;i++){
      int chunk = i*1024 + tid;
      if(chunk < ELEMS_PER_LAYER/8) dst[chunk] = src[chunk];
    }
  }

  // aggregation into LDS: thread -> (node_local = tid>>2, chunks c8b..c8b+2)
  // 4 threads/node cover 12 chunks; ids one iteration ahead.
  if(valid){
    const u16x8* xg = (const u16x8*)xh_cur;
    float a0[8], a1[8], a2[8];
    #pragma unroll
    for(int t=0;t<8;t++){ a0[t]=0.f; a1[t]=0.f; a2[t]=0.f; }
    int j1 = j0 + cnt;
    int j = j0;
    if(cnt >= 4){
      ushort4 sv = sv_pre;
      while(true){
        size_t b0 = (size_t)sv.x*12 + c8b;
        size_t b1 = (size_t)sv.y*12 + c8b;
        size_t b2 = (size_t)sv.z*12 + c8b;
        size_t b3 = (size_t)sv.w*12 + c8b;
        u16x8 v00=xg[b0], v01=xg[b0+1], v02=xg[b0+2];
        u16x8 v10=xg[b1], v11=xg[b1+1], v12=xg[b1+2];
        u16x8 v20=xg[b2], v21=xg[b2+1], v22=xg[b2+2];
        u16x8 v30=xg[b3], v31=xg[b3+1], v32=xg[b3+2];
        j += 4;
        bool more = (j + 4 <= j1);
        if(more) sv = *reinterpret_cast<const ushort4*>(ssrc + j);  // next ids in flight
        #pragma unroll
        for(int t=0;t<8;t++){
          a0[t] += (h2f(v00[t])+h2f(v10[t])) + (h2f(v20[t])+h2f(v30[t]));
          a1[t] += (h2f(v01[t])+h2f(v11[t])) + (h2f(v21[t])+h2f(v31[t]));
          a2[t] += (h2f(v02[t])+h2f(v12[t])) + (h2f(v22[t])+h2f(v32[t]));
        }
        if(!more) break;
      }
    }
    for(; j < j1; j++){
      size_t b = (size_t)ssrc[j]*12 + c8b;
      u16x8 v0=xg[b], v1=xg[b+1], v2=xg[b+2];
      #pragma unroll
      for(int t=0;t<8;t++){ a0[t]+=h2f(v0[t]); a1[t]+=h2f(v1[t]); a2[t]+=h2f(v2[t]); }
    }
    u16x8 w0, w1, w2;
    #pragma unroll
    for(int t=0;t<8;t++){ w0[t]=f2h(a0[t]); w1[t]=f2h(a1[t]); w2[t]=f2h(a2[t]); }
    aggl[(c8b+0)*256 + nl_] = w0;
    aggl[(c8b+1)*256 + nl_] = w1;
    aggl[(c8b+2)*256 + nl_] = w2;
  }
  __syncthreads();                        // the only barrier
  if(!valid) return;                      // idle waves exit after barrier

  // aggregate A fragments from LDS (chunk = ks*4+quad, row = own wave's nodes)
  f16x8 as[3];
  #pragma unroll
  for(int ks=0; ks<3; ks++)
    as[ks] = *reinterpret_cast<const f16x8*>(&aggl[(ks*4+quad)*256 + wave*16 + nidx]);

  #pragma unroll 1
  for(int tcol=0; tcol<6; tcol++){
    f32x4 air = {0.f,0.f,0.f,0.f}, aiz = {0.f,0.f,0.f,0.f}, ain = {0.f,0.f,0.f,0.f};
    f32x4 ahr = {0.f,0.f,0.f,0.f}, ahz = {0.f,0.f,0.f,0.f}, ahn = {0.f,0.f,0.f,0.f};

    #pragma unroll
    for(int ks=0; ks<3; ks++){
      const uint16_t* base = lw + (((size_t)tcol*6)*3 + ks)*512 + lane*8;
      #define BFRAG(g2) (*reinterpret_cast<const f16x8*>(base + (size_t)(g2)*3*512))
      air = MFMA16(as[ks], BFRAG(0), air);
      aiz = MFMA16(as[ks], BFRAG(1), aiz);
      ain = MFMA16(as[ks], BFRAG(2), ain);
      ahr = MFMA16(ax[ks], BFRAG(3), ahr);
      ahz = MFMA16(ax[ks], BFRAG(4), ahz);
      ahn = MFMA16(ax[ks], BFRAG(5), ahn);
      #undef BFRAG
    }

    int c = tcol*16 + nidx;
    float bir_ = b_ih[c], biz_ = b_ih[CC+c], bin_ = b_ih[2*CC+c];
    float bhr_ = b_hh[c], bhz_ = b_hh[CC+c], bhn_ = b_hh[2*CC+c];

    #pragma unroll
    for(int r=0;r<4;r++){
      int node = mtile*16 + quad*4 + r;   // C/D: row = quad*4 + reg, col = lane&15
      float ir  = air[r] + bir_;
      float iz  = aiz[r] + biz_;
      float in_ = ain[r] + bin_;
      float hr  = ahr[r] + bhr_;
      float hz  = ahz[r] + bhz_;
      float hn  = ahn[r] + bhn_;
      float rg = 1.f/(1.f + __expf(-(ir+hr)));
      float zg = 1.f/(1.f + __expf(-(iz+hz)));
      float nv = in_ + rg*hn;
      float av = fminf(fabsf(nv), 15.f);
      float e2 = __expf(2.f*av);
      float tg = 1.f - 2.f/(e2 + 1.f);
      tg = (nv < 0.f)? -tg : tg;
      size_t oi = (size_t)node*CC + c;
      float hp = h2f(xh_cur[oi]);         // h state lives in the fp16 table
      float h = (1.f - zg)*tg + zg*hp;
      if(out_f) out_f[oi] = h;            // final layer: f32 output only
      else      xh_nxt[oi] = f2h(h);      // intermediate layers: fp16 ping-pong
    }
  }
}

extern "C" void kernel_launch(void* const* d_in, const int* in_sizes, int n_in,
                              void* d_out, int out_size, void* d_ws, size_t ws_size,
                              hipStream_t stream){
  const float* x0     = (const float*)d_in[0];
  const int*   ei     = (const int*)d_in[1];
  const float* weight = (const float*)d_in[2];
  const float* w_ih   = (const float*)d_in[3];
  const float* w_hh   = (const float*)d_in[4];
  const float* b_ih   = (const float*)d_in[5];
  const float* b_hh   = (const float*)d_in[6];
  float* out = (float*)d_out;

  const int* srcv = ei;        // edge_index[0]
  const int* dstv = ei + NE;   // edge_index[1]

  char* ws = (char*)d_ws;
  size_t off = 0;
  auto carve = [&](size_t bytes)->char*{
    char* p = ws + off;
    off += (bytes + 255) & ~(size_t)255;
    return p;
  };
  int* cursor     = (int*)carve((size_t)NN*4);                   // degree counters
  uint16_t* ssrc  = (uint16_t*)carve((size_t)NN*CAP*2);          // bucketized src ids (6.4 MB)
  uint16_t* xh16A = (uint16_t*)carve((size_t)NN*CC*2);           // fp16 h table ping
  uint16_t* xh16B = (uint16_t*)carve((size_t)NN*CC*2);           // fp16 h table pong
  uint16_t* gw    = (uint16_t*)carve((size_t)NL*ELEMS_PER_LAYER*2);

  // Single-pass bucket build + prep, fused into one dispatch (disjoint
  // block ranges; scatter-bound fill overlaps VALU/VMEM-bound prep).
  hipMemsetAsync(cursor, 0, (size_t)NN*4, stream);
  k_setup<<<FILL_BLOCKS + PREP_BLOCKS, 256, 0, stream>>>(
      srcv, dstv, cursor, ssrc, (const float4*)x0, (u16x8*)xh16A, weight, w_ih, w_hh, gw);

  uint16_t* xh_cur = xh16A;
  uint16_t* xh_nxt = xh16B;
  for(int l=0; l<NL; l++){
    float* out_f = (l==NL-1) ? out : nullptr;
    k_layer<<<256, 1024, 0, stream>>>(xh_cur, xh_nxt, cursor, ssrc,
                                      gw + (size_t)l*ELEMS_PER_LAYER,
                                      b_ih, b_hh, out_f);
    uint16_t* t = xh_cur; xh_cur = xh_nxt; xh_nxt = t;
  }
}

// Round 10
// 252.346 us; speedup vs baseline: 1.2510x; 1.0011x over previous
//
#include <hip/hip_runtime.h>
#include <hip/hip_bf16.h>
#include <stdint.h>

#define NN 50000
#define NE 800000
#define CC 96
#define NL 3
#define NMT 3125          // M-tiles (16 nodes each)

// Bucketized edge lists: CAP slots per destination node. Degrees ~ Poisson(16);
// P(max degree >= 64) ~ 1e-13 -> CAP=64 is safe, and the pos<CAP guard makes
// the impossible overflow non-corrupting (drops an edge instead of OOB write).
#define CAP 64
#define CAPSH 6

// fp16 fragment-packed weights: per layer: 6 tcol x 6 sets (0-2 Wc gates, 3-5 Whh gates)
// x 3 ks x 64 lanes x 8 fp16 = 55296 elems = 108 KB
#define ELEMS_PER_LAYER 55296

// XCD-partitioned fill: 8 groups (group = blockIdx%8 -> XCD id under the
// round-robin dispatch heuristic). Each group scans ALL edges, scatters only
// dsts in its 6250-node range -> each group's ssrc slice (0.8 MB) + cursor
// slice (25 KB) stay in ONE XCD's L2. Floors established R1-R5: 800K pipelined
// device atomics ~55-58 us; LDS-counter fill (225 us) and cooperative fill
// (+95 us) both much worse. R10: fill loop manually unrolled x2 with two
// INDEPENDENT atomic chains per iteration (chain MLP).
#define FILL_GROUPS 8
#define FILL_GROUP_BLOCKS 400
#define FILL_BLOCKS (FILL_GROUPS*FILL_GROUP_BLOCKS)   // 3200
#define NODES_PER_GROUP (NN/FILL_GROUPS)              // 6250 exact

// fused setup dispatch: fill blocks (scatter-bound) then prep blocks (VALU/VMEM)
#define PREP_ITEMS (NN*CC/8 + NL*288*CC + 288*CC)
#define PREP_BLOCKS ((PREP_ITEMS + 255)/256)

typedef _Float16 f16x8 __attribute__((ext_vector_type(8)));
typedef float f32x4 __attribute__((ext_vector_type(4)));
typedef uint16_t u16x8 __attribute__((ext_vector_type(8)));

__device__ __forceinline__ uint16_t f2h(float f){
  _Float16 h = (_Float16)f;
  return __builtin_bit_cast(uint16_t, h);
}
__device__ __forceinline__ float h2f(uint16_t u){
  return (float)__builtin_bit_cast(_Float16, u);
}

// fe(tcol,g2,ks,lane,j); g2: 0-2 Wc r/z/n, 3-5 Whh r/z/n.
// B-frag (16x16x32): element (k = ks*32 + (lane>>4)*8 + j, n = lane&15).
__device__ __forceinline__ size_t frag_elem(int tcol, int g2, int ks, int lane, int j){
  return (((size_t)(tcol*6 + g2)*3 + ks)*64 + lane)*8 + j;
}

// Fused setup: blocks [0,FILL_BLOCKS) do the XCD-partitioned bucket fill with a
// single atomicAdd-with-return (returned cursor IS the degree count). Blocks
// [FILL_BLOCKS, ...) do fp16 x-table cvt + weight fold/pack (VALU/VMEM bound).
__global__ void k_setup(const int* __restrict__ srcv, const int* __restrict__ dstv,
                        int* __restrict__ cursor, uint16_t* __restrict__ ssrc,
                        const float4* __restrict__ x, u16x8* __restrict__ xh,
                        const float* __restrict__ weight, const float* __restrict__ w_ih,
                        const float* __restrict__ w_hh, uint16_t* __restrict__ gw){
  if(blockIdx.x < FILL_BLOCKS){
    int g  = blockIdx.x & 7;          // group == XCD id (round-robin dispatch)
    int bg = blockIdx.x >> 3;         // block index within group
    int dlo = g * NODES_PER_GROUP;
    const int tpg = FILL_GROUP_BLOCKS*256;      // 102400 threads/group
    // x2 unroll: pair (e, e+tpg) -> two independent atomic chains in flight.
    // NE/tpg = 7.8125 -> exactly 4 paired iterations; e2<NE guards the tail.
    for(int e = bg*256 + threadIdx.x; e < NE; e += 2*tpg){
      int e2 = e + tpg;
      int d1 = dstv[e];
      int d2 = (e2 < NE) ? dstv[e2] : -1;
      bool m1 = (unsigned)(d1 - dlo) < (unsigned)NODES_PER_GROUP;
      bool m2 = (e2 < NE) && ((unsigned)(d2 - dlo) < (unsigned)NODES_PER_GROUP);
      int s1 = m1 ? srcv[e]  : 0;
      int s2 = m2 ? srcv[e2] : 0;
      int p1 = m1 ? atomicAdd(&cursor[d1], 1) : CAP;
      int p2 = m2 ? atomicAdd(&cursor[d2], 1) : CAP;
      if(m1 && p1 < CAP) ssrc[((size_t)d1 << CAPSH) + p1] = (uint16_t)s1;
      if(m2 && p2 < CAP) ssrc[((size_t)d2 << CAPSH) + p2] = (uint16_t)s2;
    }
    return;
  }
  int idx = (blockIdx.x - FILL_BLOCKS)*256 + threadIdx.x;
  const int N8 = NN*CC/8;          // 600000
  if(idx < N8){
    float4 a = x[idx*2], b = x[idx*2+1];
    u16x8 o;
    o[0]=f2h(a.x); o[1]=f2h(a.y); o[2]=f2h(a.z); o[3]=f2h(a.w);
    o[4]=f2h(b.x); o[5]=f2h(b.y); o[6]=f2h(b.z); o[7]=f2h(b.w);
    xh[idx] = o;
    return;
  }
  int pidx = idx - N8;
  const int TOT1 = NL*288*CC;      // Wc: (l, col, k)
  const int TOT2 = 288*CC;         // Whh: (col, k), replicated to all layers
  if(pidx < TOT1){
    int k = pidx % CC;
    int col = (pidx / CC) % 288;
    int l = pidx / (CC*288);
    // Wc[k][col] = sum_k2 weight[l][k][k2] * w_ih[col][k2]
    const float4* wr = (const float4*)(weight + (size_t)(l*CC + k)*CC);
    const float4* ir = (const float4*)(w_ih + (size_t)col*CC);
    float acc = 0.f;
    #pragma unroll 4
    for(int k2=0;k2<CC/4;k2++){
      float4 a = wr[k2], b = ir[k2];
      acc += a.x*b.x + a.y*b.y + a.z*b.z + a.w*b.w;
    }
    int g = col / 96, cg = col % 96;
    int tcol = cg >> 4, n = cg & 15;
    int ks = k >> 5, r = (k & 31) >> 3, j = k & 7;
    int lane = r*16 + n;
    gw[(size_t)l*ELEMS_PER_LAYER + frag_elem(tcol, g, ks, lane, j)] = f2h(acc);
  } else {
    int idx2 = pidx - TOT1;
    if(idx2 < TOT2){
      int k = idx2 % CC;
      int col = idx2 / CC;
      uint16_t h = f2h(w_hh[(size_t)col*CC + k]);   // gh = x @ w_hh^T: B[k][col] = w_hh[col][k]
      int g = col / 96, cg = col % 96;
      int tcol = cg >> 4, n = cg & 15;
      int ks = k >> 5, r = (k & 31) >> 3, j = k & 7;
      int lane = r*16 + n;
      size_t fe = frag_elem(tcol, 3+g, ks, lane, j);
      #pragma unroll
      for(int l=0;l<NL;l++) gw[(size_t)l*ELEMS_PER_LAYER + fe] = h;
    }
  }
}

#define MFMA16(A,B,C) __builtin_amdgcn_mfma_f32_16x16x32_f16(A,B,C,0,0,0)

// Fused aggregate + dual-GEMM + GRU (R9 — proven 252.6 us, byte-identical).
// One block = 16 waves; wave w owns mtile w*256 + blockIdx.x (cyclic). Block
// aggregates its 256 nodes into LDS in A-fragment chunk-major layout
// agg[chunk=c8][node_local][16B]; ping-pong h tables (no cross-block hazard).
// LDS: 108 KB weights + 48 KB agg = 156 KB. Gather head hoisted above weight
// staging; edge-id loads software-pipelined one iteration ahead.
__global__ __launch_bounds__(1024) void k_layer(
    const uint16_t* __restrict__ xh_cur, uint16_t* __restrict__ xh_nxt,
    const int* __restrict__ counts, const uint16_t* __restrict__ ssrc,
    const uint16_t* __restrict__ gw_l,
    const float* __restrict__ b_ih, const float* __restrict__ b_hh,
    float* __restrict__ out_f)
{
  __shared__ __align__(16) uint16_t lw[ELEMS_PER_LAYER];   // 110592 B
  __shared__ u16x8 aggl[12*256];                           //  49152 B

  const int tid = threadIdx.x;
  const int wave = tid >> 6;
  const int lane = tid & 63;
  const int nidx = lane & 15;
  const int quad = lane >> 4;
  const int mtile = wave*256 + blockIdx.x;      // cyclic: all 256 blocks busy
  const bool valid = (mtile < NMT);
  const int mt = valid ? mtile : 0;

  // ---- gather head issued FIRST: counts -> first id vector (L2 chain) ------
  const int nl_ = tid >> 2;             // 0..255 ; nl_>>4 == wave
  const int c8b = (tid & 3)*3;          // 0,3,6,9
  int cnt = 0, j0 = 0;
  ushort4 sv_pre = {0,0,0,0};
  if(valid){
    int node = mt*16 + (nl_ & 15);
    cnt = counts[node]; if(cnt > CAP) cnt = CAP;   // cannot trigger
    j0 = node << CAPSH;
    if(cnt >= 4) sv_pre = *reinterpret_cast<const ushort4*>(ssrc + j0);
  }

  // h-row A fragments (global, ~600 cyc) — drain at the barrier
  f16x8 ax[3];
  {
    size_t arow = (size_t)(mt*16 + nidx)*CC;
    #pragma unroll
    for(int ks=0; ks<3; ks++)
      ax[ks] = *reinterpret_cast<const f16x8*>(xh_cur + arow + ks*32 + quad*8);
  }

  // stage weights: 6912 uint4 chunks over 1024 threads (overlaps gather head)
  {
    const uint4* src = (const uint4*)gw_l;
    uint4* dst = (uint4*)lw;
    #pragma unroll
    for(int i=0;i<7;i++){
      int chunk = i*1024 + tid;
      if(chunk < ELEMS_PER_LAYER/8) dst[chunk] = src[chunk];
    }
  }

  // aggregation into LDS: thread -> (node_local = tid>>2, chunks c8b..c8b+2)
  // 4 threads/node cover 12 chunks; ids one iteration ahead.
  if(valid){
    const u16x8* xg = (const u16x8*)xh_cur;
    float a0[8], a1[8], a2[8];
    #pragma unroll
    for(int t=0;t<8;t++){ a0[t]=0.f; a1[t]=0.f; a2[t]=0.f; }
    int j1 = j0 + cnt;
    int j = j0;
    if(cnt >= 4){
      ushort4 sv = sv_pre;
      while(true){
        size_t b0 = (size_t)sv.x*12 + c8b;
        size_t b1 = (size_t)sv.y*12 + c8b;
        size_t b2 = (size_t)sv.z*12 + c8b;
        size_t b3 = (size_t)sv.w*12 + c8b;
        u16x8 v00=xg[b0], v01=xg[b0+1], v02=xg[b0+2];
        u16x8 v10=xg[b1], v11=xg[b1+1], v12=xg[b1+2];
        u16x8 v20=xg[b2], v21=xg[b2+1], v22=xg[b2+2];
        u16x8 v30=xg[b3], v31=xg[b3+1], v32=xg[b3+2];
        j += 4;
        bool more = (j + 4 <= j1);
        if(more) sv = *reinterpret_cast<const ushort4*>(ssrc + j);  // next ids in flight
        #pragma unroll
        for(int t=0;t<8;t++){
          a0[t] += (h2f(v00[t])+h2f(v10[t])) + (h2f(v20[t])+h2f(v30[t]));
          a1[t] += (h2f(v01[t])+h2f(v11[t])) + (h2f(v21[t])+h2f(v31[t]));
          a2[t] += (h2f(v02[t])+h2f(v12[t])) + (h2f(v22[t])+h2f(v32[t]));
        }
        if(!more) break;
      }
    }
    for(; j < j1; j++){
      size_t b = (size_t)ssrc[j]*12 + c8b;
      u16x8 v0=xg[b], v1=xg[b+1], v2=xg[b+2];
      #pragma unroll
      for(int t=0;t<8;t++){ a0[t]+=h2f(v0[t]); a1[t]+=h2f(v1[t]); a2[t]+=h2f(v2[t]); }
    }
    u16x8 w0, w1, w2;
    #pragma unroll
    for(int t=0;t<8;t++){ w0[t]=f2h(a0[t]); w1[t]=f2h(a1[t]); w2[t]=f2h(a2[t]); }
    aggl[(c8b+0)*256 + nl_] = w0;
    aggl[(c8b+1)*256 + nl_] = w1;
    aggl[(c8b+2)*256 + nl_] = w2;
  }
  __syncthreads();                        // the only barrier
  if(!valid) return;                      // idle waves exit after barrier

  // aggregate A fragments from LDS (chunk = ks*4+quad, row = own wave's nodes)
  f16x8 as[3];
  #pragma unroll
  for(int ks=0; ks<3; ks++)
    as[ks] = *reinterpret_cast<const f16x8*>(&aggl[(ks*4+quad)*256 + wave*16 + nidx]);

  #pragma unroll 1
  for(int tcol=0; tcol<6; tcol++){
    f32x4 air = {0.f,0.f,0.f,0.f}, aiz = {0.f,0.f,0.f,0.f}, ain = {0.f,0.f,0.f,0.f};
    f32x4 ahr = {0.f,0.f,0.f,0.f}, ahz = {0.f,0.f,0.f,0.f}, ahn = {0.f,0.f,0.f,0.f};

    #pragma unroll
    for(int ks=0; ks<3; ks++){
      const uint16_t* base = lw + (((size_t)tcol*6)*3 + ks)*512 + lane*8;
      #define BFRAG(g2) (*reinterpret_cast<const f16x8*>(base + (size_t)(g2)*3*512))
      air = MFMA16(as[ks], BFRAG(0), air);
      aiz = MFMA16(as[ks], BFRAG(1), aiz);
      ain = MFMA16(as[ks], BFRAG(2), ain);
      ahr = MFMA16(ax[ks], BFRAG(3), ahr);
      ahz = MFMA16(ax[ks], BFRAG(4), ahz);
      ahn = MFMA16(ax[ks], BFRAG(5), ahn);
      #undef BFRAG
    }

    int c = tcol*16 + nidx;
    float bir_ = b_ih[c], biz_ = b_ih[CC+c], bin_ = b_ih[2*CC+c];
    float bhr_ = b_hh[c], bhz_ = b_hh[CC+c], bhn_ = b_hh[2*CC+c];

    #pragma unroll
    for(int r=0;r<4;r++){
      int node = mtile*16 + quad*4 + r;   // C/D: row = quad*4 + reg, col = lane&15
      float ir  = air[r] + bir_;
      float iz  = aiz[r] + biz_;
      float in_ = ain[r] + bin_;
      float hr  = ahr[r] + bhr_;
      float hz  = ahz[r] + bhz_;
      float hn  = ahn[r] + bhn_;
      float rg = 1.f/(1.f + __expf(-(ir+hr)));
      float zg = 1.f/(1.f + __expf(-(iz+hz)));
      float nv = in_ + rg*hn;
      float av = fminf(fabsf(nv), 15.f);
      float e2 = __expf(2.f*av);
      float tg = 1.f - 2.f/(e2 + 1.f);
      tg = (nv < 0.f)? -tg : tg;
      size_t oi = (size_t)node*CC + c;
      float hp = h2f(xh_cur[oi]);         // h state lives in the fp16 table
      float h = (1.f - zg)*tg + zg*hp;
      if(out_f) out_f[oi] = h;            // final layer: f32 output only
      else      xh_nxt[oi] = f2h(h);      // intermediate layers: fp16 ping-pong
    }
  }
}

extern "C" void kernel_launch(void* const* d_in, const int* in_sizes, int n_in,
                              void* d_out, int out_size, void* d_ws, size_t ws_size,
                              hipStream_t stream){
  const float* x0     = (const float*)d_in[0];
  const int*   ei     = (const int*)d_in[1];
  const float* weight = (const float*)d_in[2];
  const float* w_ih   = (const float*)d_in[3];
  const float* w_hh   = (const float*)d_in[4];
  const float* b_ih   = (const float*)d_in[5];
  const float* b_hh   = (const float*)d_in[6];
  float* out = (float*)d_out;

  const int* srcv = ei;        // edge_index[0]
  const int* dstv = ei + NE;   // edge_index[1]

  char* ws = (char*)d_ws;
  size_t off = 0;
  auto carve = [&](size_t bytes)->char*{
    char* p = ws + off;
    off += (bytes + 255) & ~(size_t)255;
    return p;
  };
  int* cursor     = (int*)carve((size_t)NN*4);                   // degree counters
  uint16_t* ssrc  = (uint16_t*)carve((size_t)NN*CAP*2);          // bucketized src ids (6.4 MB)
  uint16_t* xh16A = (uint16_t*)carve((size_t)NN*CC*2);           // fp16 h table ping
  uint16_t* xh16B = (uint16_t*)carve((size_t)NN*CC*2);           // fp16 h table pong
  uint16_t* gw    = (uint16_t*)carve((size_t)NL*ELEMS_PER_LAYER*2);

  // Single-pass bucket build + prep, fused into one dispatch (disjoint
  // block ranges; scatter-bound fill overlaps VALU/VMEM-bound prep).
  hipMemsetAsync(cursor, 0, (size_t)NN*4, stream);
  k_setup<<<FILL_BLOCKS + PREP_BLOCKS, 256, 0, stream>>>(
      srcv, dstv, cursor, ssrc, (const float4*)x0, (u16x8*)xh16A, weight, w_ih, w_hh, gw);

  uint16_t* xh_cur = xh16A;
  uint16_t* xh_nxt = xh16B;
  for(int l=0; l<NL; l++){
    float* out_f = (l==NL-1) ? out : nullptr;
    k_layer<<<256, 1024, 0, stream>>>(xh_cur, xh_nxt, cursor, ssrc,
                                      gw + (size_t)l*ELEMS_PER_LAYER,
                                      b_ih, b_hh, out_f);
    uint16_t* t = xh_cur; xh_cur = xh_nxt; xh_nxt = t;
  }
}